// Round 12
// baseline (144.136 us; speedup 1.0000x reference)
//
#include <hip/hip_runtime.h>

// inputs (B=64, N=128, N=128, L=16) f32; w (L,6,F=32) [l*192 + op*32 + f]; bias/diag_bias (F,)
#define NN 128
#define LL 16
#define FF 32

typedef float vf4 __attribute__((ext_vector_type(4)));

// 1024 blocks x 256 threads = exactly 4 blocks/CU co-resident (16 waves/CU).
// Block (b, m): owns rows m*8..m*8+7 of batch b, staged in registers.
// Per-batch producer/consumer sync over ws: rowsums -> release-add cnt[b] ->
// acquire-spin until 16 -> phase B (no input re-read). Bounded spin with a
// self-compute fallback keeps it correct even without co-residency.
__global__ __launch_bounds__(256, 4) void k_one(const float* __restrict__ in,
                                                const float* __restrict__ w,
                                                const float* __restrict__ bias,
                                                const float* __restrict__ dbias,
                                                float* __restrict__ rs,
                                                int* __restrict__ cnt,
                                                float* __restrict__ out) {
    __shared__ __align__(16) float sIn[2][NN * 20];   // 20.5 KB staging pair
    __shared__ __align__(16) float sRS[NN][20];       // 10 KB batch rowsums
    __shared__ __align__(16) float sWP[8][4][16];     // 2 KB wave partials
    __shared__ float sA[8][FF], sD[8][FF];            // 2 KB
    __shared__ float sTSp[8][16];
    __shared__ float sTS[16];
    __shared__ int sFlag;

    const int phys = blockIdx.x;          // 0..1023
    const int xcd  = phys & 7;
    const int idx  = phys >> 3;           // 0..127
    const int m    = idx & 15;            // sub-block within batch
    const int b    = (idx >> 4) * 8 + xcd;  // batch (bijective, batch co-XCD)
    const int t    = threadIdx.x;
    const int lane = t & 63;
    const int wv   = t >> 6;
    const int g8   = t & 7;               // f-quad
    const int p    = t >> 3;              // pixel lane
    const float invN  = 1.f / 50.f;
    const float invN2 = 1.f / 2500.f;

    // ---- phase A: stage own 8 rows in regs (one HBM read), rowsum them ----
    const int row0 = b * NN + m * 8;      // global row index of first owned row
    const vf4* base = reinterpret_cast<const vf4*>(in) + (size_t)row0 * 512;
    vf4 stg0[8], stg1[8];                 // row r: f4 idx t (j 0..63), 256+t (j 64..127)
#pragma unroll
    for (int r = 0; r < 8; ++r) {
        stg0[r] = base[r * 512 + t];
        stg1[r] = base[r * 512 + 256 + t];
    }
#pragma unroll
    for (int r = 0; r < 8; ++r) {
        vf4 s = stg0[r] + stg1[r];
#pragma unroll
        for (int d = 4; d < 64; d <<= 1) {
            s.x += __shfl_xor(s.x, d); s.y += __shfl_xor(s.y, d);
            s.z += __shfl_xor(s.z, d); s.w += __shfl_xor(s.w, d);
        }
        if (lane < 4) *reinterpret_cast<vf4*>(&sWP[r][wv][lane * 4]) = s;  // lane==lq
    }
    __syncthreads();
    if (t < 128) {   // 8 rows x 16 l; raw rowsums to ws (L2-resident)
        const int r = t >> 4, l = t & 15;
        rs[(size_t)(row0 + r) * LL + l] =
            sWP[r][0][l] + sWP[r][1][l] + sWP[r][2][l] + sWP[r][3][l];
    }
    __syncthreads();

    // ---- per-batch sync ----
    if (t == 0) {
        __hip_atomic_fetch_add(&cnt[b], 1, __ATOMIC_RELEASE, __HIP_MEMORY_SCOPE_AGENT);
        int iters = 0, ok = 1;
        while (__hip_atomic_load(&cnt[b], __ATOMIC_ACQUIRE, __HIP_MEMORY_SCOPE_AGENT) < 16) {
            __builtin_amdgcn_s_sleep(8);
            if (++iters > 16384) { ok = 0; break; }   // ~3.5ms bound: never hit if co-resident
        }
        sFlag = ok;
    }
    __syncthreads();

    if (sFlag) {
        // normal path: batch rowsums from ws (2 KB, same-XCD L2)
        const vf4* rsb = reinterpret_cast<const vf4*>(rs + (size_t)b * NN * LL);
#pragma unroll
        for (int k = 0; k < 2; ++k) {
            const int v = k * 256 + t, row = v >> 2, lq = v & 3;
            *reinterpret_cast<vf4*>(&sRS[row][lq * 4]) = rsb[v];
        }
    } else {
        // fallback: self-compute all 128 batch rowsums (correct w/o co-residency)
        const vf4* bin = reinterpret_cast<const vf4*>(in) + (size_t)b * NN * 512;
        for (int rr = 0; rr < 32; ++rr) {
            const int row = rr * 4 + wv;
            const vf4* src = bin + row * 512;
            float ax = 0.f, ay = 0.f, az = 0.f, aw = 0.f;
            for (int k = 0; k < 8; ++k) {
                const vf4 v = src[k * 64 + lane];
                ax += v.x; ay += v.y; az += v.z; aw += v.w;
            }
            for (int d = 4; d < 64; d <<= 1) {
                ax += __shfl_xor(ax, d); ay += __shfl_xor(ay, d);
                az += __shfl_xor(az, d); aw += __shfl_xor(aw, d);
            }
            if (lane < 4) {
                vf4 o; o.x = ax; o.y = ay; o.z = az; o.w = aw;
                *reinterpret_cast<vf4*>(&sRS[row][lane * 4]) = o;
            }
        }
    }
    __syncthreads();

    // ---- totsum (raw) ----
    if (t < 128) {
        const int l = t & 15, c = t >> 4;
        float s = 0.f;
#pragma unroll
        for (int ii = 0; ii < 16; ++ii) s += sRS[c * 16 + ii][l];
        sTSp[c][l] = s;
    }
    __syncthreads();
    if (t < 16) {
        float s = 0.f;
#pragma unroll
        for (int c = 0; c < 8; ++c) s += sTSp[c][t];
        sTS[t] = s;
    }
    __syncthreads();

    // ---- A/D for own 8 rows (256 tasks, 1/thread) ----
    {
        const int c = t >> 5, f = t & 31;
        const int rowLocal = m * 8 + c;              // batch-local row
        float dA = 0.f, tA = 0.f, dD = 0.f, tD = 0.f;
#pragma unroll
        for (int l = 0; l < LL; ++l) {
            const float rv = sRS[rowLocal][l];
            const float ts = sTS[l];
            dA = fmaf(rv, w[l * 192 +  64 + f], dA);   // op2
            dD = fmaf(rv, w[l * 192 + 128 + f], dD);   // op4
            tA = fmaf(ts, w[l * 192 +  32 + f], tA);   // op1
            tD = fmaf(ts, w[l * 192 + 160 + f], tD);   // op5
        }
        sA[c][f] = dA * invN + tA * invN2 + bias[f];
        sD[c][f] = dD * invN + tD * invN2 + dbias[f];
    }

    // ---- C quads (op3) for this thread's 4 j-columns ----
    float c4x[4] = {0.f, 0.f, 0.f, 0.f};
    float c4y[4] = {0.f, 0.f, 0.f, 0.f};
    float c4z[4] = {0.f, 0.f, 0.f, 0.f};
    float c4w[4] = {0.f, 0.f, 0.f, 0.f};
#pragma unroll
    for (int lq = 0; lq < 4; ++lq) {
        float4 w3q[4];
#pragma unroll
        for (int e = 0; e < 4; ++e)
            w3q[e] = *reinterpret_cast<const float4*>(w + (lq * 4 + e) * 192 + 96 + g8 * 4);
#pragma unroll
        for (int it = 0; it < 4; ++it) {
            const vf4 rv = *reinterpret_cast<const vf4*>(&sRS[p + 32 * it][lq * 4]);
#pragma unroll
            for (int e = 0; e < 4; ++e) {
                const float r = (e == 0) ? rv.x : (e == 1) ? rv.y : (e == 2) ? rv.z : rv.w;
                c4x[it] = fmaf(r, w3q[e].x, c4x[it]);
                c4y[it] = fmaf(r, w3q[e].y, c4y[it]);
                c4z[it] = fmaf(r, w3q[e].z, c4z[it]);
                c4w[it] = fmaf(r, w3q[e].w, c4w[it]);
            }
        }
    }
#pragma unroll
    for (int it = 0; it < 4; ++it) {
        c4x[it] *= invN; c4y[it] *= invN; c4z[it] *= invN; c4w[it] *= invN;
    }

    // ---- w0 column quads ----
    float4 w0r[LL];
#pragma unroll
    for (int l = 0; l < LL; ++l)
        w0r[l] = *reinterpret_cast<const float4*>(w + l * 192 + g8 * 4);
    __syncthreads();   // sA/sD ready

    // ---- phase B: 4 row-pairs from registers (no global input reads) ----
#pragma unroll
    for (int q = 0; q < 4; ++q) {
        {   // spill pair rows 2q,2q+1 from regs to LDS (r5-proven layout)
            const int j0 = t >> 2, lq = t & 3;
            *reinterpret_cast<vf4*>(&sIn[0][j0 * 20 + lq * 4])        = stg0[2 * q];
            *reinterpret_cast<vf4*>(&sIn[0][(64 + j0) * 20 + lq * 4]) = stg1[2 * q];
            *reinterpret_cast<vf4*>(&sIn[1][j0 * 20 + lq * 4])        = stg0[2 * q + 1];
            *reinterpret_cast<vf4*>(&sIn[1][(64 + j0) * 20 + lq * 4]) = stg1[2 * q + 1];
        }
        __syncthreads();

#pragma unroll
        for (int r = 0; r < 2; ++r) {
            const int lr = 2 * q + r;          // local row 0..7
            const int i  = m * 8 + lr;         // batch-local row
            const float4 A4 = *reinterpret_cast<const float4*>(&sA[lr][g8 * 4]);
            const float4 D4 = *reinterpret_cast<const float4*>(&sD[lr][g8 * 4]);
#pragma unroll
            for (int it = 0; it < 4; ++it) {
                const int j = p + 32 * it;
                float in_l[LL];
#pragma unroll
                for (int lq = 0; lq < 4; ++lq) {
                    const vf4 d = *reinterpret_cast<const vf4*>(&sIn[r][j * 20 + lq * 4]);
                    in_l[lq * 4 + 0] = d.x; in_l[lq * 4 + 1] = d.y;
                    in_l[lq * 4 + 2] = d.z; in_l[lq * 4 + 3] = d.w;
                }
                float a0 = A4.x + c4x[it];
                float a1 = A4.y + c4y[it];
                float a2 = A4.z + c4z[it];
                float a3 = A4.w + c4w[it];
                if (j == i) { a0 += D4.x; a1 += D4.y; a2 += D4.z; a3 += D4.w; }
#pragma unroll
                for (int l = 0; l < LL; ++l) {
                    a0 = fmaf(in_l[l], w0r[l].x, a0);
                    a1 = fmaf(in_l[l], w0r[l].y, a1);
                    a2 = fmaf(in_l[l], w0r[l].z, a2);
                    a3 = fmaf(in_l[l], w0r[l].w, a3);
                }
                vf4 o;
                o.x = fmaxf(a0, 0.f); o.y = fmaxf(a1, 0.f);
                o.z = fmaxf(a2, 0.f); o.w = fmaxf(a3, 0.f);
                float* dst = out + (((size_t)b * NN + i) * NN + j) * FF + g8 * 4;
                __builtin_nontemporal_store(o, reinterpret_cast<vf4*>(dst));
            }
        }
        __syncthreads();
    }
}

extern "C" void kernel_launch(void* const* d_in, const int* in_sizes, int n_in,
                              void* d_out, int out_size, void* d_ws, size_t ws_size,
                              hipStream_t stream) {
    const float* in    = (const float*)d_in[0];  // (64,128,128,16)
    const float* w     = (const float*)d_in[1];  // (16,6,32)
    const float* bias  = (const float*)d_in[2];  // (32,)
    const float* dbias = (const float*)d_in[3];  // (32,)
    float* out = (float*)d_out;
    float* ws  = (float*)d_ws;

    float* rs  = ws;                       // 8192*16 floats = 0.5 MiB raw rowsums
    int*   cnt = (int*)(ws + 131072);      // 64 per-batch arrival counters

    hipMemsetAsync(cnt, 0, 64 * sizeof(int), stream);   // capture-legal
    hipLaunchKernelGGL(k_one, dim3(1024), dim3(256), 0, stream,
                       in, w, bias, dbias, rs, cnt, out);
}

// Round 13
// 60.157 us; speedup vs baseline: 2.3960x; 2.3960x over previous
//
#include <hip/hip_runtime.h>

// inputs (B=64, N=128, N=128, L=16) f32; w (L,6,F=32) [l*192 + op*32 + f]; bias/diag_bias (F,)
#define NN 128
#define LL 16
#define FF 32

typedef float vf4 __attribute__((ext_vector_type(4)));

// 512 blocks x 512 threads; LDS ~74KB -> exactly 2 blocks/CU co-resident.
// Block (b, m): owns rows m*16..m*16+15 of batch b (8 blocks/batch).
// Phase A: sweeps the ENTIRE batch's rowsums itself (8x redundant reads,
// L2-deduped: co-batch blocks share an XCD via swizzle; r8 proved FETCH
// collapses to 1x input). No cross-block sync anywhere.
// Phase B: re-reads its own 16 rows (L2-hot) and streams the output.
__global__ __launch_bounds__(512, 4) void k_one(const float* __restrict__ in,
                                                const float* __restrict__ w,
                                                const float* __restrict__ bias,
                                                const float* __restrict__ dbias,
                                                float* __restrict__ out) {
    __shared__ __align__(16) float sIn[4][NN * 20];   // 41 KB: 4 staged rows, stride 20
    __shared__ __align__(16) float sRS[NN][20];       // 10 KB: batch rowsums
    __shared__ __align__(16) float sC[NN][36];        // 18 KB: C[j][f], stride 36 (aligned+conflict-free)
    __shared__ __align__(16) float sA[16][FF], sD[16][FF];  // 4 KB
    __shared__ float sTSp[8][16];
    __shared__ float sTS[16];

    const int phys = blockIdx.x;            // 0..511
    const int xcd  = phys & 7;
    const int m    = (phys >> 3) & 7;       // sub-block: rows m*16..+15
    const int b    = ((phys >> 6) & 7) * 8 + xcd;   // batch 0..63 (bijective, co-XCD per batch)
    const int t    = threadIdx.x;           // 0..511
    const int lane = t & 63;
    const int wv   = t >> 6;                // wave 0..7
    const int g8   = t & 7;                 // f-quad
    const int p    = (t >> 3) & 15;         // pixel sub-lane (16)
    const int r4   = t >> 7;                // staged-row slot 0..3
    const float invN  = 1.f / 50.f;
    const float invN2 = 1.f / 2500.f;

    const vf4* bin = reinterpret_cast<const vf4*>(in) + (size_t)b * (NN * 512);

    // ---- phase A: full-batch rowsums, one wave per row, 16 sweeps ----
#pragma unroll
    for (int rr = 0; rr < 16; ++rr) {
        const int row = rr * 8 + wv;
        const vf4* src = bin + row * 512;
        float ax = 0.f, ay = 0.f, az = 0.f, aw = 0.f;
#pragma unroll
        for (int k = 0; k < 8; ++k) {
            const vf4 v = src[k * 64 + lane];
            ax += v.x; ay += v.y; az += v.z; aw += v.w;
        }
#pragma unroll
        for (int s = 4; s < 64; s <<= 1) {
            ax += __shfl_xor(ax, s); ay += __shfl_xor(ay, s);
            az += __shfl_xor(az, s); aw += __shfl_xor(aw, s);
        }
        if (lane < 4) {   // lane == lq holds sum for l = lane*4..+3
            vf4 o; o.x = ax; o.y = ay; o.z = az; o.w = aw;
            *reinterpret_cast<vf4*>(&sRS[row][lane * 4]) = o;
        }
    }
    __syncthreads();

    // ---- totsum (raw) ----
    if (t < 128) {
        const int l = t & 15, c = t >> 4;
        float s = 0.f;
#pragma unroll
        for (int ii = 0; ii < 16; ++ii) s += sRS[c * 16 + ii][l];
        sTSp[c][l] = s;
    }
    __syncthreads();
    if (t < 16) {
        float s = 0.f;
#pragma unroll
        for (int c = 0; c < 8; ++c) s += sTSp[c][t];
        sTS[t] = s;
    }
    __syncthreads();

    // ---- A/D for own 16 rows (512 tasks, 1/thread) ----
    {
        const int c = t >> 5, f = t & 31;
        const int rowLocal = m * 16 + c;
        float dA = 0.f, tA = 0.f, dD = 0.f, tD = 0.f;
#pragma unroll
        for (int l = 0; l < LL; ++l) {
            const float rv = sRS[rowLocal][l];
            const float ts = sTS[l];
            dA = fmaf(rv, w[l * 192 +  64 + f], dA);   // op2
            dD = fmaf(rv, w[l * 192 + 128 + f], dD);   // op4
            tA = fmaf(ts, w[l * 192 +  32 + f], tA);   // op1
            tD = fmaf(ts, w[l * 192 + 160 + f], tD);   // op5
        }
        sA[c][f] = dA * invN + tA * invN2 + bias[f];
        sD[c][f] = dD * invN + tD * invN2 + dbias[f];
    }

    // ---- C[j][f] for all 128 j (4096 tasks, 8/thread) into padded LDS ----
#pragma unroll
    for (int z = 0; z < 8; ++z) {
        const int task = z * 512 + t;
        const int j = task >> 5, f = task & 31;
        float dC = 0.f;
#pragma unroll
        for (int l = 0; l < LL; ++l)
            dC = fmaf(sRS[j][l], w[l * 192 + 96 + f], dC);   // op3
        sC[j][f] = dC * invN;
    }

    // ---- w0 column quad in registers (64 VGPR; budget 128) ----
    float4 w0r[LL];
#pragma unroll
    for (int l = 0; l < LL; ++l)
        w0r[l] = *reinterpret_cast<const float4*>(w + l * 192 + g8 * 4);
    __syncthreads();   // sA/sD/sC ready

    // ---- phase B: 4 groups of 4 rows; rows re-read from L2 (r8-proven hit) ----
#pragma unroll 1
    for (int q = 0; q < 4; ++q) {
        const vf4* rb = bin + (size_t)(m * 16 + q * 4) * 512;
#pragma unroll
        for (int k = 0; k < 4; ++k) {
            const int v  = k * 512 + t;     // 0..2047 over 4 rows
            const int r  = v >> 9;
            const int vv = v & 511;
            *reinterpret_cast<vf4*>(&sIn[r][(vv >> 2) * 20 + (vv & 3) * 4]) = rb[v];
        }
        __syncthreads();

        const int lr = q * 4 + r4;          // local row 0..15
        const int i  = m * 16 + lr;         // batch-local row
        const float4 A4 = *reinterpret_cast<const float4*>(&sA[lr][g8 * 4]);
        const float4 D4 = *reinterpret_cast<const float4*>(&sD[lr][g8 * 4]);

#pragma unroll
        for (int it = 0; it < 8; ++it) {
            const int j = it * 16 + p;
            const vf4 C4 = *reinterpret_cast<const vf4*>(&sC[j][g8 * 4]);
            float in_l[LL];
#pragma unroll
            for (int lq = 0; lq < 4; ++lq) {
                const vf4 d = *reinterpret_cast<const vf4*>(&sIn[r4][j * 20 + lq * 4]);
                in_l[lq * 4 + 0] = d.x; in_l[lq * 4 + 1] = d.y;
                in_l[lq * 4 + 2] = d.z; in_l[lq * 4 + 3] = d.w;
            }
            float a0 = A4.x + C4.x;
            float a1 = A4.y + C4.y;
            float a2 = A4.z + C4.z;
            float a3 = A4.w + C4.w;
            if (j == i) { a0 += D4.x; a1 += D4.y; a2 += D4.z; a3 += D4.w; }
#pragma unroll
            for (int l = 0; l < LL; ++l) {
                a0 = fmaf(in_l[l], w0r[l].x, a0);
                a1 = fmaf(in_l[l], w0r[l].y, a1);
                a2 = fmaf(in_l[l], w0r[l].z, a2);
                a3 = fmaf(in_l[l], w0r[l].w, a3);
            }
            vf4 o;
            o.x = fmaxf(a0, 0.f); o.y = fmaxf(a1, 0.f);
            o.z = fmaxf(a2, 0.f); o.w = fmaxf(a3, 0.f);
            float* dst = out + (((size_t)b * NN + i) * NN + j) * FF + g8 * 4;
            __builtin_nontemporal_store(o, reinterpret_cast<vf4*>(dst));
        }
        __syncthreads();
    }
}

extern "C" void kernel_launch(void* const* d_in, const int* in_sizes, int n_in,
                              void* d_out, int out_size, void* d_ws, size_t ws_size,
                              hipStream_t stream) {
    const float* in    = (const float*)d_in[0];  // (64,128,128,16)
    const float* w     = (const float*)d_in[1];  // (16,6,32)
    const float* bias  = (const float*)d_in[2];  // (32,)
    const float* dbias = (const float*)d_in[3];  // (32,)
    float* out = (float*)d_out;

    hipLaunchKernelGGL(k_one, dim3(512), dim3(512), 0, stream,
                       in, w, bias, dbias, out);
}

// Round 14
// 58.727 us; speedup vs baseline: 2.4543x; 1.0243x over previous
//
#include <hip/hip_runtime.h>

// inputs (B=64, N=128, N=128, L=16) f32; w (L,6,F=32) [l*192 + op*32 + f]; bias/diag_bias (F,)
#define NN 128
#define LL 16
#define FF 32

typedef float vf4 __attribute__((ext_vector_type(4)));

// ---- proven building block 1: rowsum of 4 rows (one per wave) ----
__device__ __forceinline__ void rowsum4(const float* __restrict__ in,
                                        float* __restrict__ rs, int row0) {
    const int wave = threadIdx.x >> 6;
    const int lane = threadIdx.x & 63;
    const int row  = row0 + wave;
    const float4* src = reinterpret_cast<const float4*>(in) + (size_t)row * 512;
    float ax = 0.f, ay = 0.f, az = 0.f, aw = 0.f;
#pragma unroll
    for (int k = 0; k < 8; ++k) {
        float4 v = src[lane + 64 * k];
        ax += v.x; ay += v.y; az += v.z; aw += v.w;
    }
#pragma unroll
    for (int s = 4; s < 64; s <<= 1) {
        ax += __shfl_xor(ax, s);
        ay += __shfl_xor(ay, s);
        az += __shfl_xor(az, s);
        aw += __shfl_xor(aw, s);
    }
    if (lane < 4) {
        float4 o; o.x = ax; o.y = ay; o.z = az; o.w = aw;
        reinterpret_cast<float4*>(rs + (size_t)row * LL)[lane] = o;  // RAW rowsums
    }
}

// ---- proven building block 2: fused output for a (b, i0) row-pair ----
__device__ __forceinline__ void fused_pair(const float* __restrict__ in,
                                           const float* __restrict__ rs,
                                           const float* __restrict__ w,
                                           const float* __restrict__ bias,
                                           const float* __restrict__ dbias,
                                           float* __restrict__ out,
                                           int b, int i0) {
    __shared__ __align__(16) float sIn[2][NN * 20];  // stride 20 -> conflict-free b128
    __shared__ float sRS[NN][17];
    __shared__ float sTSp[8][16];
    __shared__ float sTS[16];
    __shared__ float sA[2][FF], sD[2][FF];
    const int t = threadIdx.x;
    const int g = t & 7;
    const int p = t >> 3;
    const float invN  = 1.f / 50.f;
    const float invN2 = 1.f / 2500.f;

    const float4* rowbase =
        reinterpret_cast<const float4*>(in + ((size_t)b * NN + i0) * (NN * LL));
#pragma unroll
    for (int k = 0; k < 4; ++k) {
        const int v  = k * 256 + t;
        const int r  = v >> 9;
        const int vv = v & 511;
        const int j  = vv >> 2, lq = vv & 3;
        const float4 d = rowbase[v];
        *reinterpret_cast<float4*>(&sIn[r][j * 20 + lq * 4]) = d;
    }
    const float4* rsb = reinterpret_cast<const float4*>(rs + (size_t)b * NN * LL);
#pragma unroll
    for (int k = 0; k < 2; ++k) {
        const int v = k * 256 + t;
        const int row = v >> 2, lq = v & 3;
        const float4 d = rsb[v];
        sRS[row][lq * 4 + 0] = d.x; sRS[row][lq * 4 + 1] = d.y;
        sRS[row][lq * 4 + 2] = d.z; sRS[row][lq * 4 + 3] = d.w;
    }
    __syncthreads();

    if (t < 128) {
        const int l = t & 15, c = t >> 4;
        float s = 0.f;
#pragma unroll
        for (int ii = 0; ii < 16; ++ii) s += sRS[c * 16 + ii][l];
        sTSp[c][l] = s;
    }
    __syncthreads();
    if (t < 16) {
        float s = 0.f;
#pragma unroll
        for (int c = 0; c < 8; ++c) s += sTSp[c][t];
        sTS[t] = s;
    }
    __syncthreads();

    if (t < 64) {
        const int r = t >> 5, f = t & 31;
        const float* rrow = &sRS[i0 + r][0];
        float dA = 0.f, tA = 0.f, dD = 0.f, tD = 0.f;
#pragma unroll
        for (int l = 0; l < LL; ++l) {
            const float rv = rrow[l];
            const float ts = sTS[l];
            dA = fmaf(rv, w[l * 192 +  64 + f], dA);   // op2
            dD = fmaf(rv, w[l * 192 + 128 + f], dD);   // op4
            tA = fmaf(ts, w[l * 192 +  32 + f], tA);   // op1
            tD = fmaf(ts, w[l * 192 + 160 + f], tD);   // op5
        }
        sA[r][f] = dA * invN + tA * invN2 + bias[f];
        sD[r][f] = dD * invN + tD * invN2 + dbias[f];
    }

    float c4x[4] = {0.f, 0.f, 0.f, 0.f};
    float c4y[4] = {0.f, 0.f, 0.f, 0.f};
    float c4z[4] = {0.f, 0.f, 0.f, 0.f};
    float c4w[4] = {0.f, 0.f, 0.f, 0.f};
#pragma unroll
    for (int l = 0; l < LL; ++l) {
        const float4 wv4 = *reinterpret_cast<const float4*>(w + l * 192 + 96 + g * 4);
#pragma unroll
        for (int it = 0; it < 4; ++it) {
            const float rv = sRS[p + 32 * it][l];
            c4x[it] = fmaf(rv, wv4.x, c4x[it]);
            c4y[it] = fmaf(rv, wv4.y, c4y[it]);
            c4z[it] = fmaf(rv, wv4.z, c4z[it]);
            c4w[it] = fmaf(rv, wv4.w, c4w[it]);
        }
    }
#pragma unroll
    for (int it = 0; it < 4; ++it) {
        c4x[it] *= invN; c4y[it] *= invN; c4z[it] *= invN; c4w[it] *= invN;
    }

    float w0r[LL][4];
#pragma unroll
    for (int l = 0; l < LL; ++l) {
        const float4 wv4 = *reinterpret_cast<const float4*>(w + l * 192 + g * 4);
        w0r[l][0] = wv4.x; w0r[l][1] = wv4.y; w0r[l][2] = wv4.z; w0r[l][3] = wv4.w;
    }
    __syncthreads();

    float4 A4[2], D4[2];
#pragma unroll
    for (int r = 0; r < 2; ++r) {
        A4[r] = *reinterpret_cast<const float4*>(&sA[r][g * 4]);
        D4[r] = *reinterpret_cast<const float4*>(&sD[r][g * 4]);
    }

#pragma unroll
    for (int it = 0; it < 4; ++it) {
        const int j = p + 32 * it;
#pragma unroll
        for (int r = 0; r < 2; ++r) {
            float in_l[LL];
#pragma unroll
            for (int lq = 0; lq < 4; ++lq) {
                const float4 d = *reinterpret_cast<const float4*>(&sIn[r][j * 20 + lq * 4]);
                in_l[lq * 4 + 0] = d.x; in_l[lq * 4 + 1] = d.y;
                in_l[lq * 4 + 2] = d.z; in_l[lq * 4 + 3] = d.w;
            }
            float a0 = A4[r].x + c4x[it];
            float a1 = A4[r].y + c4y[it];
            float a2 = A4[r].z + c4z[it];
            float a3 = A4[r].w + c4w[it];
            if (j == i0 + r) { a0 += D4[r].x; a1 += D4[r].y; a2 += D4[r].z; a3 += D4[r].w; }
#pragma unroll
            for (int l = 0; l < LL; ++l) {
                a0 = fmaf(in_l[l], w0r[l][0], a0);
                a1 = fmaf(in_l[l], w0r[l][1], a1);
                a2 = fmaf(in_l[l], w0r[l][2], a2);
                a3 = fmaf(in_l[l], w0r[l][3], a3);
            }
            vf4 o;
            o.x = fmaxf(a0, 0.f); o.y = fmaxf(a1, 0.f);
            o.z = fmaxf(a2, 0.f); o.w = fmaxf(a3, 0.f);
            float* dst = out + ((((size_t)b * NN + (i0 + r)) * NN + j) * FF) + g * 4;
            __builtin_nontemporal_store(o, reinterpret_cast<vf4*>(dst));
        }
    }
}

// K1: rowsums of batches 0..31 (rows 0..4095), 1024 blocks
__global__ __launch_bounds__(256) void k1_rowsumA(const float* __restrict__ in,
                                                  float* __restrict__ rs) {
    rowsum4(in, rs, blockIdx.x * 4);
}

// K2: blocks 0..1023 -> rowsums of batches 32..63 (rows 4096..8191), dispatched first;
//     blocks 1024..3071 -> fused output for batches 0..31.
__global__ __launch_bounds__(256) void k2_mixed(const float* __restrict__ in,
                                                const float* __restrict__ rs,
                                                const float* __restrict__ w,
                                                const float* __restrict__ bias,
                                                const float* __restrict__ dbias,
                                                float* __restrict__ out) {
    const int blk = blockIdx.x;
    if (blk < 1024) {
        rowsum4(in, (float*)rs, 4096 + blk * 4);
    } else {
        const int fblk = blk - 1024;          // 0..2047
        const int b    = fblk >> 6;           // 0..31
        const int i0   = (fblk & 63) * 2;
        fused_pair(in, rs, w, bias, dbias, out, b, i0);
    }
}

// K3: fused output for batches 32..63, 2048 blocks
__global__ __launch_bounds__(256) void k3_fusedB(const float* __restrict__ in,
                                                 const float* __restrict__ rs,
                                                 const float* __restrict__ w,
                                                 const float* __restrict__ bias,
                                                 const float* __restrict__ dbias,
                                                 float* __restrict__ out) {
    const int b  = 32 + (blockIdx.x >> 6);
    const int i0 = (blockIdx.x & 63) * 2;
    fused_pair(in, rs, w, bias, dbias, out, b, i0);
}

extern "C" void kernel_launch(void* const* d_in, const int* in_sizes, int n_in,
                              void* d_out, int out_size, void* d_ws, size_t ws_size,
                              hipStream_t stream) {
    const float* in    = (const float*)d_in[0];  // (64,128,128,16)
    const float* w     = (const float*)d_in[1];  // (16,6,32)
    const float* bias  = (const float*)d_in[2];  // (32,)
    const float* dbias = (const float*)d_in[3];  // (32,)
    float* out = (float*)d_out;
    float* rs  = (float*)d_ws;   // 8192*16 = 131072 floats raw rowsums

    hipLaunchKernelGGL(k1_rowsumA, dim3(1024), dim3(256), 0, stream, in, rs);
    hipLaunchKernelGGL(k2_mixed,   dim3(3072), dim3(256), 0, stream,
                       in, rs, w, bias, dbias, out);
    hipLaunchKernelGGL(k3_fusedB,  dim3(2048), dim3(256), 0, stream,
                       in, rs, w, bias, dbias, out);
}

// Round 15
// 51.755 us; speedup vs baseline: 2.7850x; 1.1347x over previous
//
#include <hip/hip_runtime.h>

// inputs (B=64, N=128, N=128, L=16) f32; w (L,6,F=32) [l*192 + op*32 + f]; bias/diag_bias (F,)
#define NN 128
#define LL 16
#define FF 32

typedef float vf4 __attribute__((ext_vector_type(4)));

__global__ __launch_bounds__(256) void k_rowsum(const float* __restrict__ in,
                                                float* __restrict__ rs) {
    // one wave per (b,i) row: 2048 contiguous floats = 512 float4
    const int wave = threadIdx.x >> 6;
    const int lane = threadIdx.x & 63;
    const int row  = blockIdx.x * 4 + wave;   // b*NN + i, 8192 total (ascending order)
    const float4* src = reinterpret_cast<const float4*>(in) + (size_t)row * 512;
    float ax = 0.f, ay = 0.f, az = 0.f, aw = 0.f;
#pragma unroll
    for (int k = 0; k < 8; ++k) {
        float4 v = src[lane + 64 * k];
        ax += v.x; ay += v.y; az += v.z; aw += v.w;
    }
#pragma unroll
    for (int s = 4; s < 64; s <<= 1) {
        ax += __shfl_xor(ax, s);
        ay += __shfl_xor(ay, s);
        az += __shfl_xor(az, s);
        aw += __shfl_xor(aw, s);
    }
    if (lane < 4) {
        float4 o; o.x = ax; o.y = ay; o.z = az; o.w = aw;
        reinterpret_cast<float4*>(rs + (size_t)row * LL)[lane] = o;  // RAW rowsums
    }
}

// Fused main (best-known, r11): reversed block order + nt stores.
__global__ __launch_bounds__(256) void k_fused(const float* __restrict__ in,
                                               const float* __restrict__ rs,
                                               const float* __restrict__ w,
                                               const float* __restrict__ bias,
                                               const float* __restrict__ dbias,
                                               float* __restrict__ out) {
    __shared__ __align__(16) float sIn[2][NN * 20];  // pixel stride 20 -> conflict-free b128
    __shared__ float sRS[NN][17];                    // stride 17 -> conflict-free scalar reads
    __shared__ float sTSp[8][16];
    __shared__ float sTS[16];
    __shared__ float sA[2][FF], sD[2][FF];
    const int blk = 4095 - (int)blockIdx.x;  // LIFO reversal
    const int b   = blk >> 6;
    const int i0  = (blk & 63) * 2;
    const int t   = threadIdx.x;
    const int g   = t & 7;
    const int p   = t >> 3;
    const float invN  = 1.f / 50.f;
    const float invN2 = 1.f / 2500.f;

    const float4* rowbase =
        reinterpret_cast<const float4*>(in + ((size_t)b * NN + i0) * (NN * LL));
#pragma unroll
    for (int k = 0; k < 4; ++k) {
        const int v  = k * 256 + t;
        const int r  = v >> 9;
        const int vv = v & 511;
        const int j  = vv >> 2, lq = vv & 3;
        const float4 d = rowbase[v];
        *reinterpret_cast<float4*>(&sIn[r][j * 20 + lq * 4]) = d;
    }
    const float4* rsb = reinterpret_cast<const float4*>(rs + (size_t)b * NN * LL);
#pragma unroll
    for (int k = 0; k < 2; ++k) {
        const int v = k * 256 + t;
        const int row = v >> 2, lq = v & 3;
        const float4 d = rsb[v];
        sRS[row][lq * 4 + 0] = d.x; sRS[row][lq * 4 + 1] = d.y;
        sRS[row][lq * 4 + 2] = d.z; sRS[row][lq * 4 + 3] = d.w;
    }
    __syncthreads();

    if (t < 128) {
        const int l = t & 15, c = t >> 4;
        float s = 0.f;
#pragma unroll
        for (int ii = 0; ii < 16; ++ii) s += sRS[c * 16 + ii][l];
        sTSp[c][l] = s;
    }
    __syncthreads();
    if (t < 16) {
        float s = 0.f;
#pragma unroll
        for (int c = 0; c < 8; ++c) s += sTSp[c][t];
        sTS[t] = s;
    }
    __syncthreads();

    if (t < 64) {
        const int r = t >> 5, f = t & 31;
        const float* rrow = &sRS[i0 + r][0];
        float dA = 0.f, tA = 0.f, dD = 0.f, tD = 0.f;
#pragma unroll
        for (int l = 0; l < LL; ++l) {
            const float rv = rrow[l];
            const float ts = sTS[l];
            dA = fmaf(rv, w[l * 192 +  64 + f], dA);   // op2
            dD = fmaf(rv, w[l * 192 + 128 + f], dD);   // op4
            tA = fmaf(ts, w[l * 192 +  32 + f], tA);   // op1
            tD = fmaf(ts, w[l * 192 + 160 + f], tD);   // op5
        }
        sA[r][f] = dA * invN + tA * invN2 + bias[f];
        sD[r][f] = dD * invN + tD * invN2 + dbias[f];
    }

    float c4x[4] = {0.f, 0.f, 0.f, 0.f};
    float c4y[4] = {0.f, 0.f, 0.f, 0.f};
    float c4z[4] = {0.f, 0.f, 0.f, 0.f};
    float c4w[4] = {0.f, 0.f, 0.f, 0.f};
#pragma unroll
    for (int l = 0; l < LL; ++l) {
        const float4 wv4 = *reinterpret_cast<const float4*>(w + l * 192 + 96 + g * 4);
#pragma unroll
        for (int it = 0; it < 4; ++it) {
            const float rv = sRS[p + 32 * it][l];
            c4x[it] = fmaf(rv, wv4.x, c4x[it]);
            c4y[it] = fmaf(rv, wv4.y, c4y[it]);
            c4z[it] = fmaf(rv, wv4.z, c4z[it]);
            c4w[it] = fmaf(rv, wv4.w, c4w[it]);
        }
    }
#pragma unroll
    for (int it = 0; it < 4; ++it) {
        c4x[it] *= invN; c4y[it] *= invN; c4z[it] *= invN; c4w[it] *= invN;
    }

    float w0r[LL][4];
#pragma unroll
    for (int l = 0; l < LL; ++l) {
        const float4 wv4 = *reinterpret_cast<const float4*>(w + l * 192 + g * 4);
        w0r[l][0] = wv4.x; w0r[l][1] = wv4.y; w0r[l][2] = wv4.z; w0r[l][3] = wv4.w;
    }
    __syncthreads();

    float4 A4[2], D4[2];
#pragma unroll
    for (int r = 0; r < 2; ++r) {
        A4[r] = *reinterpret_cast<const float4*>(&sA[r][g * 4]);
        D4[r] = *reinterpret_cast<const float4*>(&sD[r][g * 4]);
    }

#pragma unroll
    for (int it = 0; it < 4; ++it) {
        const int j = p + 32 * it;
#pragma unroll
        for (int r = 0; r < 2; ++r) {
            float in_l[LL];
#pragma unroll
            for (int lq = 0; lq < 4; ++lq) {
                const float4 d = *reinterpret_cast<const float4*>(&sIn[r][j * 20 + lq * 4]);
                in_l[lq * 4 + 0] = d.x; in_l[lq * 4 + 1] = d.y;
                in_l[lq * 4 + 2] = d.z; in_l[lq * 4 + 3] = d.w;
            }
            float a0 = A4[r].x + c4x[it];
            float a1 = A4[r].y + c4y[it];
            float a2 = A4[r].z + c4z[it];
            float a3 = A4[r].w + c4w[it];
            if (j == i0 + r) { a0 += D4[r].x; a1 += D4[r].y; a2 += D4[r].z; a3 += D4[r].w; }
#pragma unroll
            for (int l = 0; l < LL; ++l) {
                a0 = fmaf(in_l[l], w0r[l][0], a0);
                a1 = fmaf(in_l[l], w0r[l][1], a1);
                a2 = fmaf(in_l[l], w0r[l][2], a2);
                a3 = fmaf(in_l[l], w0r[l][3], a3);
            }
            vf4 o;
            o.x = fmaxf(a0, 0.f); o.y = fmaxf(a1, 0.f);
            o.z = fmaxf(a2, 0.f); o.w = fmaxf(a3, 0.f);
            float* dst = out + ((((size_t)b * NN + (i0 + r)) * NN + j) * FF) + g * 4;
            __builtin_nontemporal_store(o, reinterpret_cast<vf4*>(dst));  // no-allocate
        }
    }
}

extern "C" void kernel_launch(void* const* d_in, const int* in_sizes, int n_in,
                              void* d_out, int out_size, void* d_ws, size_t ws_size,
                              hipStream_t stream) {
    const float* in    = (const float*)d_in[0];  // (64,128,128,16)
    const float* w     = (const float*)d_in[1];  // (16,6,32)
    const float* bias  = (const float*)d_in[2];  // (32,)
    const float* dbias = (const float*)d_in[3];  // (32,)
    float* out = (float*)d_out;
    float* rs  = (float*)d_ws;   // 8192*16 = 131072 floats (0.5 MiB raw rowsums)

    hipLaunchKernelGGL(k_rowsum, dim3(2048), dim3(256), 0, stream, in, rs);
    hipLaunchKernelGGL(k_fused,  dim3(4096), dim3(256), 0, stream,
                       in, rs, w, bias, dbias, out);
}